// Round 1
// baseline (990.402 us; speedup 1.0000x reference)
//
#include <hip/hip_runtime.h>
#include <cstdint>
#include <cstddef>

// Problem shape (fixed by reference): B=8, S=2048, D=1024, D_FF=1024
#define BB 8
#define SS 2048
#define DD 1024

typedef unsigned short bf16_t;                                  // raw bf16 bits
typedef __attribute__((ext_vector_type(8))) short bf16x8;       // MFMA A/B frag (4 VGPRs)
typedef __attribute__((ext_vector_type(4))) float f32x4;        // MFMA C/D frag
typedef __attribute__((ext_vector_type(4))) short short4v;

#define EPI_BF16   0   // C = bf16(acc + bias), optional ReLU
#define EPI_SCORES 1   // C = mask ? acc*scale : -1e9  (f32)
#define EPI_RESID  2   // C = acc + bias + resid       (f32)

__device__ __forceinline__ bf16_t f2bf(float f) {
  union { float f; unsigned u; } v; v.f = f;
  unsigned r = v.u + 0x7FFFu + ((v.u >> 16) & 1u);   // RNE
  return (bf16_t)(r >> 16);
}

// async global->LDS, 16B per lane. LDS dst must be wave-uniform base + lane*16.
__device__ __forceinline__ void async_copy16(const void* g, void* l) {
  auto gp = reinterpret_cast<unsigned int __attribute__((address_space(1)))*>(
      reinterpret_cast<uintptr_t>(g));
  auto lp = reinterpret_cast<unsigned int __attribute__((address_space(3)))*>(
      reinterpret_cast<uintptr_t>(l));
  __builtin_amdgcn_global_load_lds(gp, lp, 16, 0, 0);
}

// ---------------------------------------------------------------------------
// m97-style NT GEMM: C[M,N] = A[M,K] * BT[N,K]^T, all bf16 in, f32 accumulate.
// 128x128 block tile, BK=32, 4 waves (2x2), each wave 4x4 of 16x16x32 MFMA.
// Requires M%128==0, N%128==0, K%32==0 (true for all calls here).
// ---------------------------------------------------------------------------
template <int EPI, bool RELU>
__global__ __launch_bounds__(256)
void gemm_nt(const bf16_t* __restrict__ A, const bf16_t* __restrict__ BT,
             void* __restrict__ Cv,
             const float* __restrict__ bias,   // [N] or null
             const float* __restrict__ resid,  // [M,N] f32 (EPI_RESID)
             const int* __restrict__ mask,     // [sMask per batch] (EPI_SCORES)
             int M, int N, int K,
             long long sA, long long sB, long long sC, long long sMask,
             float scale)
{
  __shared__ __align__(16) bf16_t As[128 * 32];
  __shared__ __align__(16) bf16_t Bs[128 * 32];

  const int tid  = threadIdx.x;
  const int wave = tid >> 6;
  const int lane = tid & 63;
  const int wr   = wave >> 1, wc = wave & 1;
  const int lr   = lane & 15, quad = lane >> 4;

  const int n0 = blockIdx.x * 128;
  const int m0 = blockIdx.y * 128;
  const int z  = blockIdx.z;

  const bf16_t* Ab = A  + (size_t)z * (size_t)sA;
  const bf16_t* Bb = BT + (size_t)z * (size_t)sB;

  f32x4 acc[4][4];
#pragma unroll
  for (int i = 0; i < 4; i++)
#pragma unroll
    for (int j = 0; j < 4; j++)
#pragma unroll
      for (int r = 0; r < 4; r++) acc[i][j][r] = 0.0f;

  // staging chunks: 512 x 16B per 8KB tile; thread handles chunks tid, tid+256
  const int c0 = tid, c1 = tid + 256;
  const int ar0 = c0 >> 2, ak0 = (c0 & 3) * 8;
  const int ar1 = c1 >> 2, ak1 = (c1 & 3) * 8;

  for (int kt = 0; kt < K; kt += 32) {
    async_copy16(Ab + (size_t)(m0 + ar0) * K + kt + ak0, (char*)As + c0 * 16);
    async_copy16(Ab + (size_t)(m0 + ar1) * K + kt + ak1, (char*)As + c1 * 16);
    async_copy16(Bb + (size_t)(n0 + ar0) * K + kt + ak0, (char*)Bs + c0 * 16);
    async_copy16(Bb + (size_t)(n0 + ar1) * K + kt + ak1, (char*)Bs + c1 * 16);
    __syncthreads();   // compiler drains vmcnt before s_barrier

    bf16x8 a[4], b[4];
#pragma unroll
    for (int i = 0; i < 4; i++)
      a[i] = *(const bf16x8*)(As + (wr * 64 + i * 16 + lr) * 32 + quad * 8);
#pragma unroll
    for (int j = 0; j < 4; j++)
      b[j] = *(const bf16x8*)(Bs + (wc * 64 + j * 16 + lr) * 32 + quad * 8);

#pragma unroll
    for (int i = 0; i < 4; i++)
#pragma unroll
      for (int j = 0; j < 4; j++)
        acc[i][j] = __builtin_amdgcn_mfma_f32_16x16x32_bf16(a[i], b[j], acc[i][j], 0, 0, 0);
    __syncthreads();
  }

  // epilogue: C/D layout col = lane&15, row = quad*4 + r  [verified m89/m91]
#pragma unroll
  for (int i = 0; i < 4; i++) {
    const int gmb = m0 + wr * 64 + i * 16 + quad * 4;
#pragma unroll
    for (int j = 0; j < 4; j++) {
      const int gn = n0 + wc * 64 + j * 16 + lr;
#pragma unroll
      for (int r = 0; r < 4; r++) {
        float v = acc[i][j][r];
        const size_t off = (size_t)z * (size_t)sC + (size_t)(gmb + r) * N + gn;
        if constexpr (EPI == EPI_BF16) {
          float bv = bias ? bias[gn] : 0.0f;
          v += bv;
          if (RELU) v = v > 0.0f ? v : 0.0f;
          ((bf16_t*)Cv)[off] = f2bf(v);
        } else if constexpr (EPI == EPI_SCORES) {
          const int mk = mask[(size_t)z * (size_t)sMask + gn];
          ((float*)Cv)[off] = mk ? v * scale : -1e9f;
        } else {
          ((float*)Cv)[off] = v + bias[gn] + resid[(size_t)(gmb + r) * N + gn];
        }
      }
    }
  }
}

// ---------------------------------------------------------------------------
// LayerNorm over D=1024: one block / row, 256 threads x float4. Output bf16.
// ---------------------------------------------------------------------------
__global__ __launch_bounds__(256)
void ln_kernel(const float* __restrict__ x, const float* __restrict__ g,
               const float* __restrict__ b, bf16_t* __restrict__ out)
{
  const int row  = blockIdx.x;
  const int t    = threadIdx.x;
  const int wave = t >> 6, lane = t & 63;
  const float4 v = ((const float4*)(x + (size_t)row * DD))[t];

  float s = v.x + v.y + v.z + v.w;
#pragma unroll
  for (int o = 32; o > 0; o >>= 1) s += __shfl_down(s, o);
  __shared__ float red1[4], red2[4];
  if (lane == 0) red1[wave] = s;
  __syncthreads();
  const float mu = (red1[0] + red1[1] + red1[2] + red1[3]) * (1.0f / DD);

  const float d0 = v.x - mu, d1 = v.y - mu, d2 = v.z - mu, d3 = v.w - mu;
  float ss = d0 * d0 + d1 * d1 + d2 * d2 + d3 * d3;
#pragma unroll
  for (int o = 32; o > 0; o >>= 1) ss += __shfl_down(ss, o);
  if (lane == 0) red2[wave] = ss;
  __syncthreads();
  const float var = (red2[0] + red2[1] + red2[2] + red2[3]) * (1.0f / DD);
  const float rs  = rsqrtf(var + 1e-5f);

  const float4 gg = ((const float4*)g)[t];
  const float4 bb = ((const float4*)b)[t];
  short4v o;
  o.x = (short)f2bf(d0 * rs * gg.x + bb.x);
  o.y = (short)f2bf(d1 * rs * gg.y + bb.y);
  o.z = (short)f2bf(d2 * rs * gg.z + bb.z);
  o.w = (short)f2bf(d3 * rs * gg.w + bb.w);
  *(short4v*)(out + (size_t)row * DD + t * 4) = o;
}

// ---------------------------------------------------------------------------
// Row softmax over S=2048, in-place f32. One block / row.
// ---------------------------------------------------------------------------
__global__ __launch_bounds__(256)
void softmax_kernel(float* __restrict__ w)
{
  float* p = w + (size_t)blockIdx.x * SS;
  const int t = threadIdx.x;
  const int wave = t >> 6, lane = t & 63;
  float4 v0 = ((float4*)p)[t];
  float4 v1 = ((float4*)p)[t + 256];

  float m = fmaxf(fmaxf(fmaxf(v0.x, v0.y), fmaxf(v0.z, v0.w)),
                  fmaxf(fmaxf(v1.x, v1.y), fmaxf(v1.z, v1.w)));
#pragma unroll
  for (int o = 32; o > 0; o >>= 1) m = fmaxf(m, __shfl_down(m, o));
  __shared__ float red1[4], red2[4];
  if (lane == 0) red1[wave] = m;
  __syncthreads();
  m = fmaxf(fmaxf(red1[0], red1[1]), fmaxf(red1[2], red1[3]));

  v0.x = __expf(v0.x - m); v0.y = __expf(v0.y - m);
  v0.z = __expf(v0.z - m); v0.w = __expf(v0.w - m);
  v1.x = __expf(v1.x - m); v1.y = __expf(v1.y - m);
  v1.z = __expf(v1.z - m); v1.w = __expf(v1.w - m);

  float s = v0.x + v0.y + v0.z + v0.w + v1.x + v1.y + v1.z + v1.w;
#pragma unroll
  for (int o = 32; o > 0; o >>= 1) s += __shfl_down(s, o);
  if (lane == 0) red2[wave] = s;
  __syncthreads();
  const float inv = 1.0f / (red2[0] + red2[1] + red2[2] + red2[3]);

  v0.x *= inv; v0.y *= inv; v0.z *= inv; v0.w *= inv;
  v1.x *= inv; v1.y *= inv; v1.z *= inv; v1.w *= inv;
  ((float4*)p)[t] = v0;
  ((float4*)p)[t + 256] = v1;
}

// ---------------------------------------------------------------------------
// Tiled transpose (+convert) to bf16: in [R,C] -> out [C,R]. block (32,8).
// ---------------------------------------------------------------------------
template <typename ST>
__global__ __launch_bounds__(256)
void transpose_to_bf16(const ST* __restrict__ in, bf16_t* __restrict__ out, int R, int C)
{
  __shared__ float tile[32][33];
  const int tx = threadIdx.x, ty = threadIdx.y;
  const size_t zo = (size_t)blockIdx.z * (size_t)R * (size_t)C;
  const int c0 = blockIdx.x * 32, r0 = blockIdx.y * 32;
#pragma unroll
  for (int k = 0; k < 32; k += 8) {
    ST raw = in[zo + (size_t)(r0 + ty + k) * C + (c0 + tx)];
    float v;
    if constexpr (sizeof(ST) == 2) {
      v = __uint_as_float(((unsigned)(unsigned short)raw) << 16);
    } else {
      v = (float)raw;
    }
    tile[ty + k][tx] = v;
  }
  __syncthreads();
#pragma unroll
  for (int k = 0; k < 32; k += 8)
    out[zo + (size_t)(c0 + ty + k) * R + (r0 + tx)] = f2bf(tile[tx][ty + k]);
}

// ---------------------------------------------------------------------------
// f32 -> bf16 bulk convert (x4 per thread)
// ---------------------------------------------------------------------------
__global__ __launch_bounds__(256)
void cvt_f32_bf16(const float* __restrict__ in, bf16_t* __restrict__ out, long long n4)
{
  const long long i = (long long)blockIdx.x * 256 + threadIdx.x;
  if (i < n4) {
    float4 v = ((const float4*)in)[i];
    short4v o = { (short)f2bf(v.x), (short)f2bf(v.y), (short)f2bf(v.z), (short)f2bf(v.w) };
    ((short4v*)out)[i] = o;
  }
}

// ---------------------------------------------------------------------------
extern "C" void kernel_launch(void* const* d_in, const int* in_sizes, int n_in,
                              void* d_out, int out_size, void* d_ws, size_t ws_size,
                              hipStream_t stream)
{
  const float* x    = (const float*)d_in[0];
  const int*   mask = (const int*)d_in[1];
  const float* ln1g = (const float*)d_in[2];
  const float* ln1b = (const float*)d_in[3];
  const float* Wq   = (const float*)d_in[4];
  const float* bq   = (const float*)d_in[5];
  const float* Wk   = (const float*)d_in[6];
  const float* bk   = (const float*)d_in[7];
  const float* Wo   = (const float*)d_in[8];
  const float* bo   = (const float*)d_in[9];
  const float* ln2g = (const float*)d_in[10];
  const float* ln2b = (const float*)d_in[11];
  const float* W1   = (const float*)d_in[12];
  const float* b1   = (const float*)d_in[13];
  const float* W2   = (const float*)d_in[14];
  const float* b2   = (const float*)d_in[15];

  float* out  = (float*)d_out;                       // (B,S,D) f32
  float* wout = out + (size_t)BB * SS * DD;          // (B,S,S) f32 attention weights

  // ---- workspace layout (total ~138 MB), regions reused across phases ----
  char* ws = (char*)d_ws;
  size_t off = 0;
  auto alloc = [&](size_t bytes) {
    char* p = ws + off; off += (bytes + 255) & ~(size_t)255; return p;
  };
  bf16_t* WqT = (bf16_t*)alloc((size_t)DD * DD * 2);
  bf16_t* WkT = (bf16_t*)alloc((size_t)DD * DD * 2);
  bf16_t* WoT = (bf16_t*)alloc((size_t)DD * DD * 2);
  bf16_t* W1T = (bf16_t*)alloc((size_t)DD * DD * 2);
  bf16_t* W2T = (bf16_t*)alloc((size_t)DD * DD * 2);
  char* R1 = alloc((size_t)64 * 1024 * 1024);  // xn+Q -> w_bf -> x2
  char* R2 = alloc((size_t)32 * 1024 * 1024);  // K -> attnV -> h
  char* R3 = alloc((size_t)32 * 1024 * 1024);  // KT -> xn2

  bf16_t* xn  = (bf16_t*)R1;                       // (B*S, D) bf16
  bf16_t* Q   = (bf16_t*)(R1 + (size_t)32 * 1024 * 1024);
  bf16_t* wbf = (bf16_t*)R1;                       // (B,S,S) bf16
  float*  x2  = (float*)R1;                        // (B*S, D) f32
  bf16_t* Kb  = (bf16_t*)R2;                       // (B,S,D) bf16  (K == V)
  bf16_t* aV  = (bf16_t*)R2;                       // (B,S,D) bf16
  bf16_t* h   = (bf16_t*)R2;                       // (B*S, D_FF) bf16
  bf16_t* KT  = (bf16_t*)R3;                       // (B,D,S) bf16  (V^T)
  bf16_t* xn2 = (bf16_t*)R3;                       // (B*S, D) bf16

  const dim3 tb(256);
  const dim3 tt(32, 8);
  const long long SD = (long long)SS * DD;         // per-batch Q/K elems
  const long long SSb = (long long)SS * SS;        // per-batch score elems

  // 1. weights -> transposed bf16 [N][K]
  transpose_to_bf16<float><<<dim3(32, 32, 1), tt, 0, stream>>>(Wq, WqT, DD, DD);
  transpose_to_bf16<float><<<dim3(32, 32, 1), tt, 0, stream>>>(Wk, WkT, DD, DD);
  transpose_to_bf16<float><<<dim3(32, 32, 1), tt, 0, stream>>>(Wo, WoT, DD, DD);
  transpose_to_bf16<float><<<dim3(32, 32, 1), tt, 0, stream>>>(W1, W1T, DD, DD);
  transpose_to_bf16<float><<<dim3(32, 32, 1), tt, 0, stream>>>(W2, W2T, DD, DD);

  // 2. xn = LN1(x)
  ln_kernel<<<dim3(BB * SS), tb, 0, stream>>>(x, ln1g, ln1b, xn);

  // 3. Q = xn@Wq + bq ; K = xn@Wk + bk   (bf16 out)
  gemm_nt<EPI_BF16, false><<<dim3(8, 128, 1), tb, 0, stream>>>(
      xn, WqT, Q, bq, nullptr, nullptr, BB * SS, DD, DD, 0, 0, 0, 0, 1.0f);
  gemm_nt<EPI_BF16, false><<<dim3(8, 128, 1), tb, 0, stream>>>(
      xn, WkT, Kb, bk, nullptr, nullptr, BB * SS, DD, DD, 0, 0, 0, 0, 1.0f);

  // 4. scores = QK^T/32, masked -> wout (f32)
  gemm_nt<EPI_SCORES, false><<<dim3(16, 16, BB), tb, 0, stream>>>(
      Q, Kb, wout, nullptr, nullptr, mask, SS, SS, DD, SD, SD, SSb, SS, 0.03125f);

  // 5. softmax rows (in place)
  softmax_kernel<<<dim3(BB * SS), tb, 0, stream>>>(wout);

  // 6. V^T: transpose K per batch (v == k per reference bug)
  transpose_to_bf16<bf16_t><<<dim3(32, 64, BB), tt, 0, stream>>>(Kb, KT, SS, DD);

  // 7. w -> bf16
  cvt_f32_bf16<<<dim3((unsigned)((size_t)BB * SS * SS / 4 / 256)), tb, 0, stream>>>(
      wout, wbf, (long long)BB * SS * SS / 4);

  // 8. attnV = w @ V   (bf16 out)
  gemm_nt<EPI_BF16, false><<<dim3(8, 16, BB), tb, 0, stream>>>(
      wbf, KT, aV, nullptr, nullptr, nullptr, SS, DD, SS, SSb, SD, SD, 0, 1.0f);

  // 9. x2 = x + attnV@Wo + bo  (f32)
  gemm_nt<EPI_RESID, false><<<dim3(8, 128, 1), tb, 0, stream>>>(
      aV, WoT, x2, bo, x, nullptr, BB * SS, DD, DD, 0, 0, 0, 0, 1.0f);

  // 10. xn2 = LN2(x2)
  ln_kernel<<<dim3(BB * SS), tb, 0, stream>>>(x2, ln2g, ln2b, xn2);

  // 11. h = relu(xn2@W1 + b1)  (bf16)
  gemm_nt<EPI_BF16, true><<<dim3(8, 128, 1), tb, 0, stream>>>(
      xn2, W1T, h, b1, nullptr, nullptr, BB * SS, DD, DD, 0, 0, 0, 0, 1.0f);

  // 12. out = x2 + h@W2 + b2  (f32)
  gemm_nt<EPI_RESID, false><<<dim3(8, 128, 1), tb, 0, stream>>>(
      h, W2T, out, b2, x2, nullptr, BB * SS, DD, DD, 0, 0, 0, 0, 1.0f);
}

// Round 2
// 890.621 us; speedup vs baseline: 1.1120x; 1.1120x over previous
//
#include <hip/hip_runtime.h>
#include <cstdint>
#include <cstddef>

// Problem shape (fixed by reference): B=8, S=2048, D=1024, D_FF=1024
#define BB 8
#define SS 2048
#define DD 1024

typedef unsigned short bf16_t;                                  // raw bf16 bits
typedef __attribute__((ext_vector_type(8))) short bf16x8;       // MFMA A/B frag (4 VGPRs)
typedef __attribute__((ext_vector_type(4))) float f32x4;        // MFMA C/D frag
typedef __attribute__((ext_vector_type(4))) short short4v;

#define EPI_BF16   0   // C = bf16(acc + bias), optional ReLU
#define EPI_SCORES 1   // C = mask ? acc*scale : -1e9  (f32)
#define EPI_RESID  2   // C = acc + bias + resid       (f32, resid same-element RMW safe)

__device__ __forceinline__ bf16_t f2bf(float f) {
  union { float f; unsigned u; } v; v.f = f;
  unsigned r = v.u + 0x7FFFu + ((v.u >> 16) & 1u);   // RNE
  return (bf16_t)(r >> 16);
}

// async global->LDS, 16B per lane. LDS dst must be wave-uniform base + lane*16.
__device__ __forceinline__ void async_copy16(const void* g, void* l) {
  auto gp = reinterpret_cast<unsigned int __attribute__((address_space(1)))*>(
      reinterpret_cast<uintptr_t>(g));
  auto lp = reinterpret_cast<unsigned int __attribute__((address_space(3)))*>(
      reinterpret_cast<uintptr_t>(l));
  __builtin_amdgcn_global_load_lds(gp, lp, 16, 0, 0);
}

// ---------------------------------------------------------------------------
// NT GEMM: C[M,N] = A[M,K] * BT[N,K]^T, bf16 in, f32 accumulate.
// 128x128 tile, BK=32, 4 waves (2x2), each wave 4x4 of 16x16x32 MFMA.
// 1D grid with XCD-locality swizzle: block b -> XCD b%8 (HW round-robin);
// idx = (b&7)*C + (b>>3) gives each XCD a CONTIGUOUS chunk of the
// (z, n-chunk, m, n_in) tile order -> A-tile hot in L2 across its n-sweep,
// B-chunk L2-resident. nchunk = n-tiles per chunk (working-set knob).
// ---------------------------------------------------------------------------
template <int EPI, bool RELU>
__global__ __launch_bounds__(256)
void gemm_nt(const bf16_t* __restrict__ A, const bf16_t* __restrict__ BT,
             void* __restrict__ Cv,
             const float* __restrict__ bias,   // [<=ldc] or null
             const float* __restrict__ bias2,  // second-half bias (fused QK) or null
             const float* __restrict__ resid,  // [M,ldc] f32 (EPI_RESID)
             const int* __restrict__ mask,     // per-batch mask (EPI_SCORES)
             int Mt, int Nt, int Z, int nchunk,
             int K, int lda, int ldb, int ldc,
             long long sA, long long sB, long long sC, long long sMask,
             float scale)
{
  __shared__ __align__(16) bf16_t As[128 * 32];
  __shared__ __align__(16) bf16_t Bs[128 * 32];

  // ---- XCD swizzle ----
  const int b    = blockIdx.x;
  const int Cchunk = (Z * Mt * Nt) >> 3;           // blocks per XCD (divisible by 8)
  int idx = (b & 7) * Cchunk + (b >> 3);
  const int per_z = Mt * Nt;
  const int z = idx / per_z;  idx -= z * per_z;
  const int per_nc = Mt * nchunk;
  const int nc = idx / per_nc; idx -= nc * per_nc;
  const int mt = idx / nchunk;
  const int nin = idx - mt * nchunk;
  const int m0 = mt * 128;
  const int n0 = (nc * nchunk + nin) * 128;

  const int tid  = threadIdx.x;
  const int wave = tid >> 6;
  const int lane = tid & 63;
  const int wr   = wave >> 1, wc = wave & 1;
  const int lr   = lane & 15, quad = lane >> 4;

  const bf16_t* Ab = A  + (size_t)z * (size_t)sA;
  const bf16_t* Bb = BT + (size_t)z * (size_t)sB;

  f32x4 acc[4][4];
#pragma unroll
  for (int i = 0; i < 4; i++)
#pragma unroll
    for (int j = 0; j < 4; j++)
#pragma unroll
      for (int r = 0; r < 4; r++) acc[i][j][r] = 0.0f;

  // staging chunks: 512 x 16B per 8KB tile; thread handles chunks tid, tid+256
  const int c0 = tid, c1 = tid + 256;
  const int ar0 = c0 >> 2, ak0 = (c0 & 3) * 8;
  const int ar1 = c1 >> 2, ak1 = (c1 & 3) * 8;

  for (int kt = 0; kt < K; kt += 32) {
    async_copy16(Ab + (size_t)(m0 + ar0) * lda + kt + ak0, (char*)As + c0 * 16);
    async_copy16(Ab + (size_t)(m0 + ar1) * lda + kt + ak1, (char*)As + c1 * 16);
    async_copy16(Bb + (size_t)(n0 + ar0) * ldb + kt + ak0, (char*)Bs + c0 * 16);
    async_copy16(Bb + (size_t)(n0 + ar1) * ldb + kt + ak1, (char*)Bs + c1 * 16);
    __syncthreads();

    bf16x8 a[4], bfr[4];
#pragma unroll
    for (int i = 0; i < 4; i++)
      a[i] = *(const bf16x8*)(As + (wr * 64 + i * 16 + lr) * 32 + quad * 8);
#pragma unroll
    for (int j = 0; j < 4; j++)
      bfr[j] = *(const bf16x8*)(Bs + (wc * 64 + j * 16 + lr) * 32 + quad * 8);

#pragma unroll
    for (int i = 0; i < 4; i++)
#pragma unroll
      for (int j = 0; j < 4; j++)
        acc[i][j] = __builtin_amdgcn_mfma_f32_16x16x32_bf16(a[i], bfr[j], acc[i][j], 0, 0, 0);
    __syncthreads();
  }

  // epilogue: C/D layout col = lane&15, row = quad*4 + r  [verified m89/m91]
#pragma unroll
  for (int i = 0; i < 4; i++) {
    const int gmb = m0 + wr * 64 + i * 16 + quad * 4;
#pragma unroll
    for (int j = 0; j < 4; j++) {
      const int gn = n0 + wc * 64 + j * 16 + lr;
      float bv = 0.0f;
      if constexpr (EPI != EPI_SCORES) {
        // gn>=1024 is block-uniform (n-tiles are 128-wide, 1024-aligned split)
        bv = (bias2 && gn >= 1024) ? bias2[gn - 1024] : (bias ? bias[gn] : 0.0f);
      }
#pragma unroll
      for (int r = 0; r < 4; r++) {
        float v = acc[i][j][r];
        const size_t off = (size_t)z * (size_t)sC + (size_t)(gmb + r) * ldc + gn;
        if constexpr (EPI == EPI_BF16) {
          v += bv;
          if (RELU) v = v > 0.0f ? v : 0.0f;
          ((bf16_t*)Cv)[off] = f2bf(v);
        } else if constexpr (EPI == EPI_SCORES) {
          const int mk = mask[(size_t)z * (size_t)sMask + gn];
          ((float*)Cv)[off] = mk ? v * scale : -1e9f;
        } else {
          ((float*)Cv)[off] = v + bv + resid[(size_t)(gmb + r) * ldc + gn];
        }
      }
    }
  }
}

// ---------------------------------------------------------------------------
// LayerNorm over D=1024: one block / row, 256 threads x float4. Output bf16.
// ---------------------------------------------------------------------------
__global__ __launch_bounds__(256)
void ln_kernel(const float* __restrict__ x, const float* __restrict__ g,
               const float* __restrict__ b, bf16_t* __restrict__ out)
{
  const int row  = blockIdx.x;
  const int t    = threadIdx.x;
  const int wave = t >> 6, lane = t & 63;
  const float4 v = ((const float4*)(x + (size_t)row * DD))[t];

  float s = v.x + v.y + v.z + v.w;
#pragma unroll
  for (int o = 32; o > 0; o >>= 1) s += __shfl_down(s, o);
  __shared__ float red1[4], red2[4];
  if (lane == 0) red1[wave] = s;
  __syncthreads();
  const float mu = (red1[0] + red1[1] + red1[2] + red1[3]) * (1.0f / DD);

  const float d0 = v.x - mu, d1 = v.y - mu, d2 = v.z - mu, d3 = v.w - mu;
  float ss = d0 * d0 + d1 * d1 + d2 * d2 + d3 * d3;
#pragma unroll
  for (int o = 32; o > 0; o >>= 1) ss += __shfl_down(ss, o);
  if (lane == 0) red2[wave] = ss;
  __syncthreads();
  const float var = (red2[0] + red2[1] + red2[2] + red2[3]) * (1.0f / DD);
  const float rs  = rsqrtf(var + 1e-5f);

  const float4 gg = ((const float4*)g)[t];
  const float4 bb = ((const float4*)b)[t];
  short4v o;
  o.x = (short)f2bf(d0 * rs * gg.x + bb.x);
  o.y = (short)f2bf(d1 * rs * gg.y + bb.y);
  o.z = (short)f2bf(d2 * rs * gg.z + bb.z);
  o.w = (short)f2bf(d3 * rs * gg.w + bb.w);
  *(short4v*)(out + (size_t)row * DD + t * 4) = o;
}

// ---------------------------------------------------------------------------
// Row softmax over S=2048, dual output: f32 in-place + bf16 copy.
// ---------------------------------------------------------------------------
__global__ __launch_bounds__(256)
void softmax_kernel(float* __restrict__ w, bf16_t* __restrict__ wb)
{
  const size_t rowoff = (size_t)blockIdx.x * SS;
  float* p = w + rowoff;
  const int t = threadIdx.x;
  const int wave = t >> 6, lane = t & 63;
  float4 v0 = ((float4*)p)[t];
  float4 v1 = ((float4*)p)[t + 256];

  float m = fmaxf(fmaxf(fmaxf(v0.x, v0.y), fmaxf(v0.z, v0.w)),
                  fmaxf(fmaxf(v1.x, v1.y), fmaxf(v1.z, v1.w)));
#pragma unroll
  for (int o = 32; o > 0; o >>= 1) m = fmaxf(m, __shfl_down(m, o));
  __shared__ float red1[4], red2[4];
  if (lane == 0) red1[wave] = m;
  __syncthreads();
  m = fmaxf(fmaxf(red1[0], red1[1]), fmaxf(red1[2], red1[3]));

  v0.x = __expf(v0.x - m); v0.y = __expf(v0.y - m);
  v0.z = __expf(v0.z - m); v0.w = __expf(v0.w - m);
  v1.x = __expf(v1.x - m); v1.y = __expf(v1.y - m);
  v1.z = __expf(v1.z - m); v1.w = __expf(v1.w - m);

  float s = v0.x + v0.y + v0.z + v0.w + v1.x + v1.y + v1.z + v1.w;
#pragma unroll
  for (int o = 32; o > 0; o >>= 1) s += __shfl_down(s, o);
  if (lane == 0) red2[wave] = s;
  __syncthreads();
  const float inv = 1.0f / (red2[0] + red2[1] + red2[2] + red2[3]);

  v0.x *= inv; v0.y *= inv; v0.z *= inv; v0.w *= inv;
  v1.x *= inv; v1.y *= inv; v1.z *= inv; v1.w *= inv;
  ((float4*)p)[t] = v0;
  ((float4*)p)[t + 256] = v1;

  short4v o0 = { (short)f2bf(v0.x), (short)f2bf(v0.y), (short)f2bf(v0.z), (short)f2bf(v0.w) };
  short4v o1 = { (short)f2bf(v1.x), (short)f2bf(v1.y), (short)f2bf(v1.z), (short)f2bf(v1.w) };
  *(short4v*)(wb + rowoff + t * 4)         = o0;
  *(short4v*)(wb + rowoff + (t + 256) * 4) = o1;
}

// ---------------------------------------------------------------------------
// Tiled transpose (+convert) to bf16: in [R,C](ldin) -> out [C,R]. block (32,8).
// ---------------------------------------------------------------------------
template <typename ST>
__global__ __launch_bounds__(256)
void transpose_to_bf16(const ST* __restrict__ in, bf16_t* __restrict__ out,
                       int R, int C, int ldin, long long inB, long long outB)
{
  __shared__ float tile[32][33];
  const int tx = threadIdx.x, ty = threadIdx.y;
  const size_t zi = (size_t)blockIdx.z * (size_t)inB;
  const size_t zo = (size_t)blockIdx.z * (size_t)outB;
  const int c0 = blockIdx.x * 32, r0 = blockIdx.y * 32;
#pragma unroll
  for (int k = 0; k < 32; k += 8) {
    ST raw = in[zi + (size_t)(r0 + ty + k) * ldin + (c0 + tx)];
    float v;
    if constexpr (sizeof(ST) == 2) {
      v = __uint_as_float(((unsigned)(unsigned short)raw) << 16);
    } else {
      v = (float)raw;
    }
    tile[ty + k][tx] = v;
  }
  __syncthreads();
#pragma unroll
  for (int k = 0; k < 32; k += 8)
    out[zo + (size_t)(c0 + ty + k) * R + (r0 + tx)] = f2bf(tile[tx][ty + k]);
}

// ---------------------------------------------------------------------------
extern "C" void kernel_launch(void* const* d_in, const int* in_sizes, int n_in,
                              void* d_out, int out_size, void* d_ws, size_t ws_size,
                              hipStream_t stream)
{
  const float* x    = (const float*)d_in[0];
  const int*   mask = (const int*)d_in[1];
  const float* ln1g = (const float*)d_in[2];
  const float* ln1b = (const float*)d_in[3];
  const float* Wq   = (const float*)d_in[4];
  const float* bq   = (const float*)d_in[5];
  const float* Wk   = (const float*)d_in[6];
  const float* bk   = (const float*)d_in[7];
  const float* Wo   = (const float*)d_in[8];
  const float* bo   = (const float*)d_in[9];
  const float* ln2g = (const float*)d_in[10];
  const float* ln2b = (const float*)d_in[11];
  const float* W1   = (const float*)d_in[12];
  const float* b1   = (const float*)d_in[13];
  const float* W2   = (const float*)d_in[14];
  const float* b2   = (const float*)d_in[15];

  float* out  = (float*)d_out;                       // (B,S,D) f32, 64MB
  float* wout = out + (size_t)BB * SS * DD;          // (B,S,S) f32, 128MB

  // ---- workspace layout (~170 MB), plus d_out-region reuse ----
  char* ws = (char*)d_ws;
  size_t off = 0;
  auto alloc = [&](size_t bytes) {
    char* p = ws + off; off += (bytes + 255) & ~(size_t)255; return p;
  };
  bf16_t* WqkT = (bf16_t*)alloc((size_t)2 * DD * DD * 2);   // [2048,1024] = WqT ; WkT
  bf16_t* WoT  = (bf16_t*)alloc((size_t)DD * DD * 2);
  bf16_t* W1T  = (bf16_t*)alloc((size_t)DD * DD * 2);
  bf16_t* W2T  = (bf16_t*)alloc((size_t)DD * DD * 2);
  bf16_t* QKb  = (bf16_t*)alloc((size_t)BB * SS * 2 * DD * 2);  // [16384,2048] bf16, 64MB
  char*   Rwb  = alloc((size_t)64 * 1024 * 1024);               // wbf -> xn2+h
  bf16_t* aV   = (bf16_t*)alloc((size_t)BB * SS * DD * 2);      // 32MB

  bf16_t* wbf = (bf16_t*)Rwb;                      // (B,S,S) bf16, dies after w@V
  bf16_t* xn2 = (bf16_t*)Rwb;                      // (B*S,D) bf16 (after wbf dead)
  bf16_t* h   = (bf16_t*)(Rwb + (size_t)32 * 1024 * 1024);  // (B*S,D_FF) bf16

  // d_out reuse: xn lives in wout region (dead before scores written);
  // KT lives in out region (dead before x2 born); x2 lives in out region
  // (final GEMM reads resid=x2 and overwrites same element in-thread).
  bf16_t* xn = (bf16_t*)wout;                      // (B*S,D) bf16, dies step 3
  bf16_t* KT = (bf16_t*)out;                       // (B,D,S) bf16, steps 6-7
  float*  x2 = out;                                // (B*S,D) f32, from step 8

  const dim3 tb(256);
  const dim3 tt(32, 8);
  const long long SD   = (long long)SS * DD;       // 2M elems
  const long long S2   = (long long)SS * SS;       // 4M elems
  const long long QKs  = (long long)SS * 2 * DD;   // per-batch elems in QKb

  // 1. weights -> transposed bf16 [N][K]; Wq,Wk concatenated
  transpose_to_bf16<float><<<dim3(32, 32, 1), tt, 0, stream>>>(Wq, WqkT, DD, DD, DD, 0, 0);
  transpose_to_bf16<float><<<dim3(32, 32, 1), tt, 0, stream>>>(Wk, WqkT + (size_t)DD * DD, DD, DD, DD, 0, 0);
  transpose_to_bf16<float><<<dim3(32, 32, 1), tt, 0, stream>>>(Wo, WoT, DD, DD, DD, 0, 0);
  transpose_to_bf16<float><<<dim3(32, 32, 1), tt, 0, stream>>>(W1, W1T, DD, DD, DD, 0, 0);
  transpose_to_bf16<float><<<dim3(32, 32, 1), tt, 0, stream>>>(W2, W2T, DD, DD, DD, 0, 0);

  // 2. xn = LN1(x)
  ln_kernel<<<dim3(BB * SS), tb, 0, stream>>>(x, ln1g, ln1b, xn);

  // 3. QK = xn @ [Wq|Wk] + [bq|bk]   (bf16, [16384,2048])
  gemm_nt<EPI_BF16, false><<<dim3(2048), tb, 0, stream>>>(
      xn, WqkT, QKb, bq, bk, nullptr, nullptr,
      /*Mt,Nt,Z,nc*/ 128, 16, 1, 8, /*K,lda,ldb,ldc*/ DD, DD, DD, 2 * DD,
      0, 0, 0, 0, 1.0f);

  // 4. scores = Q K^T / 32, masked -> wout (f32). Per-XCD chunk == one batch.
  gemm_nt<EPI_SCORES, false><<<dim3(2048), tb, 0, stream>>>(
      QKb, QKb + DD, wout, nullptr, nullptr, nullptr, mask,
      16, 16, BB, 8, /*K,lda,ldb,ldc*/ DD, 2 * DD, 2 * DD, SS,
      QKs, QKs, S2, SS, 0.03125f);

  // 5. softmax rows -> wout (f32) + wbf (bf16)
  softmax_kernel<<<dim3(BB * SS), tb, 0, stream>>>(wout, wbf);

  // 6. V^T: transpose K (cols 1024..2047 of QKb) per batch -> KT [D,S]
  transpose_to_bf16<bf16_t><<<dim3(32, 64, BB), tt, 0, stream>>>(
      QKb + DD, KT, SS, DD, 2 * DD, QKs, SD);

  // 7. attnV = w @ V   (bf16). nchunk=4 keeps B-chunk (2MB) L2-hot.
  gemm_nt<EPI_BF16, false><<<dim3(1024), tb, 0, stream>>>(
      wbf, KT, aV, nullptr, nullptr, nullptr, nullptr,
      16, 8, BB, 4, /*K,lda,ldb,ldc*/ SS, SS, SS, DD,
      S2, SD, SD, 0, 1.0f);

  // 8. x2 = x + attnV@Wo + bo  (f32, into out region)
  gemm_nt<EPI_RESID, false><<<dim3(1024), tb, 0, stream>>>(
      aV, WoT, x2, bo, nullptr, x, nullptr,
      128, 8, 1, 8, DD, DD, DD, DD, 0, 0, 0, 0, 1.0f);

  // 9. xn2 = LN2(x2)
  ln_kernel<<<dim3(BB * SS), tb, 0, stream>>>(x2, ln2g, ln2b, xn2);

  // 10. h = relu(xn2@W1 + b1)  (bf16)
  gemm_nt<EPI_BF16, true><<<dim3(1024), tb, 0, stream>>>(
      xn2, W1T, h, b1, nullptr, nullptr, nullptr,
      128, 8, 1, 8, DD, DD, DD, DD, 0, 0, 0, 0, 1.0f);

  // 11. out = x2 + h@W2 + b2  (f32, elementwise RMW of out region)
  gemm_nt<EPI_RESID, false><<<dim3(1024), tb, 0, stream>>>(
      h, W2T, out, b2, nullptr, x2, nullptr,
      128, 8, 1, 8, DD, DD, DD, DD, 0, 0, 0, 0, 1.0f);
}